// Round 8
// baseline (1436.317 us; speedup 1.0000x reference)
//
#include <hip/hip_runtime.h>
#include <cstdint>
#include <cstddef>

// Problem constants
#define B_    16
#define N_    512
#define L_    2048
#define DIM_  768
#define M_    8
#define CE_   64
#define VOCAB_ 1024
#define H_    128
#define G4_   512   // 4*H
#define XDIM_ 128   // 2*CE

typedef __bf16 bf16x8 __attribute__((ext_vector_type(8)));
typedef float  f32x4  __attribute__((ext_vector_type(4)));

__device__ __forceinline__ unsigned short f2bf(float f) {
    unsigned u = __float_as_uint(f);
    u += 0x7fffu + ((u >> 16) & 1u);   // RNE
    return (unsigned short)(u >> 16);
}

// ---------------------------------------------------------------------------
// Generic fp32 tiled GEMM: C[M,N] = A[M,K] @ B + bias1 (+bias2)
//   TRANSB=false: B is [K,N] row-major.  TRANSB=true: B is [N,K] row-major.
// 128x128 tile, BK=8, 256 threads, 8x8 per thread. R6: double-buffered LDS,
// one barrier per K-step, next-tile loads issued before compute.
// ---------------------------------------------------------------------------
template<bool TRANSB>
__global__ __launch_bounds__(256) void gemm_f32(
    const float* __restrict__ A, const float* __restrict__ Bm,
    const float* __restrict__ bias1, const float* __restrict__ bias2,
    float* __restrict__ C, int M, int N, int K)
{
    __shared__ float As[2][8][128];
    __shared__ float Bs[2][8][128];
    const int t  = threadIdx.x;
    const int tx = t & 15, ty = t >> 4;
    const int m0 = blockIdx.y * 128, n0 = blockIdx.x * 128;
    const int arow = t >> 1, ahalf = (t & 1) * 4;
    const int bk = t >> 5, bn = (t & 31) * 4;

    float acc[8][8];
#pragma unroll
    for (int i = 0; i < 8; i++)
#pragma unroll
        for (int j = 0; j < 8; j++) acc[i][j] = 0.f;

    {
        float4 av = *(const float4*)(A + (size_t)(m0 + arow) * K + ahalf);
        float4 bv;
        if (TRANSB) bv = *(const float4*)(Bm + (size_t)(n0 + arow) * K + ahalf);
        else        bv = *(const float4*)(Bm + (size_t)bk * N + n0 + bn);
        As[0][ahalf + 0][arow] = av.x;
        As[0][ahalf + 1][arow] = av.y;
        As[0][ahalf + 2][arow] = av.z;
        As[0][ahalf + 3][arow] = av.w;
        if (TRANSB) {
            Bs[0][ahalf + 0][arow] = bv.x;
            Bs[0][ahalf + 1][arow] = bv.y;
            Bs[0][ahalf + 2][arow] = bv.z;
            Bs[0][ahalf + 3][arow] = bv.w;
        } else {
            *(float4*)&Bs[0][bk][bn] = bv;
        }
    }
    __syncthreads();

    int cur = 0;
    for (int k0 = 0; k0 < K; k0 += 8) {
        const bool more = (k0 + 8 < K);
        float4 av, bv;
        if (more) {
            av = *(const float4*)(A + (size_t)(m0 + arow) * K + (k0 + 8) + ahalf);
            if (TRANSB) bv = *(const float4*)(Bm + (size_t)(n0 + arow) * K + (k0 + 8) + ahalf);
            else        bv = *(const float4*)(Bm + (size_t)(k0 + 8 + bk) * N + n0 + bn);
        }
#pragma unroll
        for (int k = 0; k < 8; k++) {
            float a[8], bb[8];
            *(float4*)&a[0]  = *(const float4*)&As[cur][k][ty * 8];
            *(float4*)&a[4]  = *(const float4*)&As[cur][k][ty * 8 + 4];
            *(float4*)&bb[0] = *(const float4*)&Bs[cur][k][tx * 8];
            *(float4*)&bb[4] = *(const float4*)&Bs[cur][k][tx * 8 + 4];
#pragma unroll
            for (int i = 0; i < 8; i++)
#pragma unroll
                for (int j = 0; j < 8; j++)
                    acc[i][j] = fmaf(a[i], bb[j], acc[i][j]);
        }
        if (more) {
            const int nxt = cur ^ 1;
            As[nxt][ahalf + 0][arow] = av.x;
            As[nxt][ahalf + 1][arow] = av.y;
            As[nxt][ahalf + 2][arow] = av.z;
            As[nxt][ahalf + 3][arow] = av.w;
            if (TRANSB) {
                Bs[nxt][ahalf + 0][arow] = bv.x;
                Bs[nxt][ahalf + 1][arow] = bv.y;
                Bs[nxt][ahalf + 2][arow] = bv.z;
                Bs[nxt][ahalf + 3][arow] = bv.w;
            } else {
                *(float4*)&Bs[nxt][bk][bn] = bv;
            }
        }
        __syncthreads();
        cur ^= 1;
    }

    float bia[8];
#pragma unroll
    for (int j = 0; j < 8; j++) {
        int gn = n0 + tx * 8 + j;
        bia[j] = bias1[gn] + (bias2 ? bias2[gn] : 0.f);
    }
#pragma unroll
    for (int i = 0; i < 8; i++) {
        size_t row = (size_t)(m0 + ty * 8 + i) * N + n0 + tx * 8;
#pragma unroll
        for (int j = 0; j < 8; j++)
            C[row + j] = acc[i][j] + bia[j];
    }
}

// ---------------------------------------------------------------------------
// Exclusive scan of word lengths per batch (N_=512 words, one block per batch)
// ---------------------------------------------------------------------------
__global__ __launch_bounds__(512) void scan_lens(const int* __restrict__ lens,
                                                 int* __restrict__ off)
{
    const int b = blockIdx.x, t = threadIdx.x;
    __shared__ int s[512];
    int v = lens[b * N_ + t];
    s[t] = v;
    __syncthreads();
    for (int d = 1; d < 512; d <<= 1) {
        int u = (t >= d) ? s[t - d] : 0;
        __syncthreads();
        s[t] += u;
        __syncthreads();
    }
    off[b * N_ + t] = s[t] - v;   // exclusive prefix
}

// ---------------------------------------------------------------------------
// dec_char gather + zero-fill of the pad half (replaces the 16 MB memset)
// ---------------------------------------------------------------------------
__global__ __launch_bounds__(256) void char_gather(const int* __restrict__ ids,
                                                   const float* __restrict__ emb,
                                                   float* __restrict__ x)
{
    int g   = blockIdx.x * 8 + (threadIdx.x >> 5);   // (b,l) flat, 8 per block
    int l32 = threadIdx.x & 31;
    int id  = ids[g];
    float4 v;
    if (l32 < 16) v = *(const float4*)(emb + (size_t)id * CE_ + l32 * 4);
    else          v = make_float4(0.f, 0.f, 0.f, 0.f);
    *(float4*)(x + (size_t)g * XDIM_ + l32 * 4) = v;
}

// ---------------------------------------------------------------------------
// Ragged scatter: x[b, off+m, 64+c] = rep[b,n,m,c] for m < len, off+m < L
// ---------------------------------------------------------------------------
__global__ __launch_bounds__(512) void scatter_pad(const float* __restrict__ rep,
                                                   const int* __restrict__ lens,
                                                   const int* __restrict__ off,
                                                   float* __restrict__ x)
{
    int word = blockIdx.x;            // b*512 + n
    int b = word >> 9;
    int m  = threadIdx.x >> 6;
    int cc = threadIdx.x & 63;
    int len = lens[word];
    if (m < len) {
        int dst = off[word] + m;
        if (dst < L_) {
            x[((size_t)b * L_ + dst) * XDIM_ + CE_ + cc] =
                rep[((size_t)word * M_ + m) * CE_ + cc];
        }
    }
}

// ---------------------------------------------------------------------------
// LSTM recurrence, R7: 4 waves (256 thr) per batch, 1 wave/SIMD.
//
// Counter evidence (R6): VALUBusy 3.26% GPU = ~52%/active-SIMD = ~565 cyc of
// issue per 1085-cyc step with the 8-wave design (2 lockstep waves/SIMD).
// Step = issue + exposed serial chain. R7 attacks issue:
//  - each wave owns TWO 16-wide col-groups (jA = w*32+l15, jB = jA+16):
//    same 128 MFMA/CU/step (32/wave, per-SIMD MFMA issue unchanged), but
//    half the waves -> half the per-CU trans/VALU issue;
//  - quad-parity activation split: each lane holds both j-chains post-MFMA
//    and SELECTS one by (quad&1) (4 cndmask) -> 10 trans/lane, zero
//    redundancy doubling; quad0 writes h[jA], quad1 writes h[jB];
//  - issue diet: persistent accumulators (C-in regs 1..3 are never read ->
//    no zeroing, write only acc[0]=gx preact = 8 movs not 20); gx loads via
//    one pointer advanced 2048 B/step + 13-bit imm offsets (no per-step addr
//    VALU, no tail clamp -- the <=2-row overrun lands in the unused upper
//    half of d_out);
//  - __launch_bounds__(256,1): 1 wave/SIMD -> VGPR cap 512, no spill
//    (R4/R5 lesson: VGPR_Count==64 means poisoned experiment).
// ---------------------------------------------------------------------------
__global__ __launch_bounds__(256, 1) void lstm_rec(const float* __restrict__ gx,   // [B,L,512]
                                                   const float* __restrict__ Whh,  // [512,128]
                                                   float* __restrict__ hs)         // [B,L,128]
{
    const int b    = blockIdx.x;
    const int tid  = threadIdx.x;
    const int wave = tid >> 6, lane = tid & 63;
    const int quad = lane >> 4, l15 = lane & 15;
    const int jA   = wave * 32 + l15;          // first col-group owned by this wave

    __shared__ __align__(16) unsigned short hbuf[2][128];
    if (tid < 128) hbuf[0][tid] = 0;           // h_{-1} = 0 (bf16 zero bits)

    // B fragments: bfrag[jg][q][kk] = W_hh[q*128 + jA + jg*16][kk*32 + quad*8 + 0..7]
    bf16x8 bfrag[2][4][4];
#pragma unroll
    for (int jg = 0; jg < 2; jg++)
#pragma unroll
        for (int q = 0; q < 4; q++) {
            const float* wrow = Whh + (size_t)(q * 128 + jA + jg * 16) * H_;
#pragma unroll
            for (int kk = 0; kk < 4; kk++) {
                int kb = kk * 32 + quad * 8;
                float4 w0 = *(const float4*)(wrow + kb);
                float4 w1 = *(const float4*)(wrow + kb + 4);
                union { unsigned short u[8]; bf16x8 v; } U;
                U.u[0] = f2bf(w0.x); U.u[1] = f2bf(w0.y); U.u[2] = f2bf(w0.z); U.u[3] = f2bf(w0.w);
                U.u[4] = f2bf(w1.x); U.u[5] = f2bf(w1.y); U.u[6] = f2bf(w1.z); U.u[7] = f2bf(w1.w);
                bfrag[jg][q][kk] = U.v;
            }
        }

    // gx loads: one per-lane pointer at column jA of row (t+2), advanced one
    // row (2048 B) per step; the 8 gate/jg offsets are 13-bit immediates.
    const float* gp = gx + (size_t)b * L_ * G4_ + jA;
    float pf[2][2][4];   // [u][jg][q], ring depth 2
#pragma unroll
    for (int u = 0; u < 2; u++)
#pragma unroll
        for (int jg = 0; jg < 2; jg++)
#pragma unroll
            for (int q = 0; q < 4; q++)
                pf[u][jg][q] = gp[(size_t)u * G4_ + q * 128 + jg * 16];
    gp += 2 * G4_;   // now points at row t=2

    // persistent accumulators: regs 1..3 carry stale garbage (never read)
    f32x4 aAi = {0,0,0,0}, aAf = aAi, aAg = aAi, aAo = aAi;
    f32x4 aBi = aAi, aBf = aAi, aBg = aAi, aBo = aAi;

    float c = 0.f;
    float* hsb = hs + (size_t)b * L_ * H_;
    const bool hi = (quad & 1);                // which chain this lane finishes
    const int  jw = jA + (quad & 1) * 16;      // the j quads 0/1 write

    __syncthreads();   // hbuf init visible

#define RCP_(x) __builtin_amdgcn_rcpf(x)
#define MFMA_(a, bb, cc) __builtin_amdgcn_mfma_f32_16x16x32_bf16(a, bb, cc, 0, 0, 0)

    for (int t0 = 0; t0 < L_; t0 += 2) {
#pragma unroll
        for (int u = 0; u < 2; u++) {
            const int t  = t0 + u;
            const int pb = t & 1;

            // A fragments (h broadcast across rows), shared by both col-groups
            bf16x8 a0 = *(const bf16x8*)&hbuf[pb][0 * 32 + quad * 8];
            bf16x8 a1 = *(const bf16x8*)&hbuf[pb][1 * 32 + quad * 8];
            bf16x8 a2 = *(const bf16x8*)&hbuf[pb][2 * 32 + quad * 8];
            bf16x8 a3 = *(const bf16x8*)&hbuf[pb][3 * 32 + quad * 8];

            // C-in reg0 = gx pre-activation (only reg read downstream)
            aAi[0] = pf[u][0][0]; aAf[0] = pf[u][0][1];
            aAg[0] = pf[u][0][2]; aAo[0] = pf[u][0][3];
            aBi[0] = pf[u][1][0]; aBf[0] = pf[u][1][1];
            aBg[0] = pf[u][1][2]; aBo[0] = pf[u][1][3];

            // refill slot u for t+2 (in flight across the raw barrier)
#pragma unroll
            for (int jg = 0; jg < 2; jg++)
#pragma unroll
                for (int q = 0; q < 4; q++)
                    pf[u][jg][q] = gp[q * 128 + jg * 16];
            gp += G4_;

            // 8 independent 4-deep MFMA chains (2 col-groups x 4 gates)
            aAg = MFMA_(a0, bfrag[0][2][0], aAg);
            aBg = MFMA_(a0, bfrag[1][2][0], aBg);
            aAi = MFMA_(a0, bfrag[0][0][0], aAi);
            aBi = MFMA_(a0, bfrag[1][0][0], aBi);
            aAf = MFMA_(a0, bfrag[0][1][0], aAf);
            aBf = MFMA_(a0, bfrag[1][1][0], aBf);
            aAo = MFMA_(a0, bfrag[0][3][0], aAo);
            aBo = MFMA_(a0, bfrag[1][3][0], aBo);

            aAg = MFMA_(a1, bfrag[0][2][1], aAg);
            aBg = MFMA_(a1, bfrag[1][2][1], aBg);
            aAi = MFMA_(a1, bfrag[0][0][1], aAi);
            aBi = MFMA_(a1, bfrag[1][0][1], aBi);
            aAf = MFMA_(a1, bfrag[0][1][1], aAf);
            aBf = MFMA_(a1, bfrag[1][1][1], aBf);
            aAo = MFMA_(a1, bfrag[0][3][1], aAo);
            aBo = MFMA_(a1, bfrag[1][3][1], aBo);

            aAg = MFMA_(a2, bfrag[0][2][2], aAg);
            aBg = MFMA_(a2, bfrag[1][2][2], aBg);
            aAi = MFMA_(a2, bfrag[0][0][2], aAi);
            aBi = MFMA_(a2, bfrag[1][0][2], aBi);
            aAf = MFMA_(a2, bfrag[0][1][2], aAf);
            aBf = MFMA_(a2, bfrag[1][1][2], aBf);
            aAo = MFMA_(a2, bfrag[0][3][2], aAo);
            aBo = MFMA_(a2, bfrag[1][3][2], aBo);

            aAg = MFMA_(a3, bfrag[0][2][3], aAg);
            aBg = MFMA_(a3, bfrag[1][2][3], aBg);
            aAi = MFMA_(a3, bfrag[0][0][3], aAi);
            aBi = MFMA_(a3, bfrag[1][0][3], aBi);
            aAf = MFMA_(a3, bfrag[0][1][3], aAf);
            aBf = MFMA_(a3, bfrag[1][1][3], aBf);
            aAo = MFMA_(a3, bfrag[0][3][3], aAo);
            aBo = MFMA_(a3, bfrag[1][3][3], aBo);

            // quad-parity select: one activation chain per lane
            float gi = hi ? aBi[0] : aAi[0];
            float gf = hi ? aBf[0] : aAf[0];
            float gg = hi ? aBg[0] : aAg[0];
            float go = hi ? aBo[0] : aAo[0];

            float tg = 1.f - 2.f * RCP_(__expf(2.f * gg) + 1.f);
            float si = RCP_(1.f + __expf(-gi));
            float sf = RCP_(1.f + __expf(-gf));
            float so = RCP_(1.f + __expf(-go));
            c = sf * c + si * tg;
            float tc = 1.f - 2.f * RCP_(__expf(2.f * c) + 1.f);
            float h = so * tc;

            unsigned hr;
            asm("v_cvt_pk_bf16_f32 %0, %1, %2" : "=v"(hr) : "v"(h), "v"(h));
            if (quad < 2) {
                hbuf[pb ^ 1][jw] = (unsigned short)hr;
                hsb[(size_t)t * H_ + jw] = h;
            }
            // LDS-only drain + barrier (proven R2 form)
            asm volatile("s_waitcnt lgkmcnt(0)\n\ts_barrier" ::: "memory");
        }
    }
#undef RCP_
#undef MFMA_
}

// ---------------------------------------------------------------------------
// Launch. Workspace layout (bytes):
//   rep : [0, 16 MiB)            8192 x 512 fp32
//   x   : [16 MiB, 32 MiB)       16 x 2048 x 128 fp32
//   hs  : [32 MiB, 48 MiB)       16 x 2048 x 128 fp32
//   off : [48 MiB, +32 KiB)      16 x 512 int
// gx (64 MiB) staged in d_out (128 MiB), consumed before the final GEMM;
// lstm_rec's prefetch may read <=2 rows past gx -- still inside d_out.
// ---------------------------------------------------------------------------
extern "C" void kernel_launch(void* const* d_in, const int* in_sizes, int n_in,
                              void* d_out, int out_size, void* d_ws, size_t ws_size,
                              hipStream_t stream)
{
    (void)in_sizes; (void)n_in; (void)out_size; (void)ws_size;
    const float* dec_hidden = (const float*)d_in[0];
    const int*   ids        = (const int*)d_in[1];
    const int*   lens       = (const int*)d_in[2];
    const float* char_emb   = (const float*)d_in[3];
    const float* W_proj     = (const float*)d_in[4];
    const float* b_proj     = (const float*)d_in[5];
    const float* W_ih       = (const float*)d_in[6];
    const float* W_hh       = (const float*)d_in[7];
    const float* b_ih       = (const float*)d_in[8];
    const float* b_hh       = (const float*)d_in[9];
    const float* W_pred     = (const float*)d_in[10];
    const float* b_pred     = (const float*)d_in[11];
    float* out = (float*)d_out;

    char* ws   = (char*)d_ws;
    float* rep = (float*)(ws);
    float* x   = (float*)(ws + (size_t)16 * 1024 * 1024);
    float* hs  = (float*)(ws + (size_t)32 * 1024 * 1024);
    int*   off = (int*)  (ws + (size_t)48 * 1024 * 1024);
    float* gx  = out;   // staged in output buffer, consumed before final GEMM

    // 1) rep = dec_hidden @ W_proj + b_proj   [8192,768]x[768,512]
    gemm_f32<false><<<dim3(4, 64), 256, 0, stream>>>(
        dec_hidden, W_proj, b_proj, nullptr, rep, B_ * N_, 512, DIM_);

    // 2) per-batch exclusive scan of word lengths
    scan_lens<<<B_, 512, 0, stream>>>(lens, off);

    // 3) build x = concat(char_emb[ids], 0-pad) then scatter rep into the pad
    char_gather<<<(B_ * L_) / 8, 256, 0, stream>>>(ids, char_emb, x);
    scatter_pad<<<B_ * N_, 512, 0, stream>>>(rep, lens, off, x);

    // 4) gx = x @ W_ih^T + b_ih + b_hh        [32768,128]x[512,128]^T
    gemm_f32<true><<<dim3(4, 256), 256, 0, stream>>>(
        x, W_ih, b_ih, b_hh, gx, B_ * L_, G4_, XDIM_);

    // 5) sequential LSTM (the critical path): 4 waves per batch
    lstm_rec<<<B_, 256, 0, stream>>>(gx, W_hh, hs);

    // 6) out = hs @ W_pred + b_pred           [32768,128]x[128,1024]
    gemm_f32<false><<<dim3(8, 256), 256, 0, stream>>>(
        hs, W_pred, b_pred, nullptr, out, B_ * L_, VOCAB_, H_);
}

// Round 9
// 1304.171 us; speedup vs baseline: 1.1013x; 1.1013x over previous
//
#include <hip/hip_runtime.h>
#include <cstdint>
#include <cstddef>

// Problem constants
#define B_    16
#define N_    512
#define L_    2048
#define DIM_  768
#define M_    8
#define CE_   64
#define VOCAB_ 1024
#define H_    128
#define G4_   512   // 4*H
#define XDIM_ 128   // 2*CE

typedef __bf16 bf16x8 __attribute__((ext_vector_type(8)));
typedef float  f32x4  __attribute__((ext_vector_type(4)));

__device__ __forceinline__ unsigned short f2bf(float f) {
    unsigned u = __float_as_uint(f);
    u += 0x7fffu + ((u >> 16) & 1u);   // RNE
    return (unsigned short)(u >> 16);
}

// ---------------------------------------------------------------------------
// Generic fp32 tiled GEMM: C[M,N] = A[M,K] @ B + bias1 (+bias2)
//   TRANSB=false: B is [K,N] row-major.  TRANSB=true: B is [N,K] row-major.
// 128x128 tile, BK=8, 256 threads, 8x8 per thread. R6: double-buffered LDS,
// one barrier per K-step, next-tile loads issued before compute.
// ---------------------------------------------------------------------------
template<bool TRANSB>
__global__ __launch_bounds__(256) void gemm_f32(
    const float* __restrict__ A, const float* __restrict__ Bm,
    const float* __restrict__ bias1, const float* __restrict__ bias2,
    float* __restrict__ C, int M, int N, int K)
{
    __shared__ float As[2][8][128];
    __shared__ float Bs[2][8][128];
    const int t  = threadIdx.x;
    const int tx = t & 15, ty = t >> 4;
    const int m0 = blockIdx.y * 128, n0 = blockIdx.x * 128;
    const int arow = t >> 1, ahalf = (t & 1) * 4;
    const int bk = t >> 5, bn = (t & 31) * 4;

    float acc[8][8];
#pragma unroll
    for (int i = 0; i < 8; i++)
#pragma unroll
        for (int j = 0; j < 8; j++) acc[i][j] = 0.f;

    {
        float4 av = *(const float4*)(A + (size_t)(m0 + arow) * K + ahalf);
        float4 bv;
        if (TRANSB) bv = *(const float4*)(Bm + (size_t)(n0 + arow) * K + ahalf);
        else        bv = *(const float4*)(Bm + (size_t)bk * N + n0 + bn);
        As[0][ahalf + 0][arow] = av.x;
        As[0][ahalf + 1][arow] = av.y;
        As[0][ahalf + 2][arow] = av.z;
        As[0][ahalf + 3][arow] = av.w;
        if (TRANSB) {
            Bs[0][ahalf + 0][arow] = bv.x;
            Bs[0][ahalf + 1][arow] = bv.y;
            Bs[0][ahalf + 2][arow] = bv.z;
            Bs[0][ahalf + 3][arow] = bv.w;
        } else {
            *(float4*)&Bs[0][bk][bn] = bv;
        }
    }
    __syncthreads();

    int cur = 0;
    for (int k0 = 0; k0 < K; k0 += 8) {
        const bool more = (k0 + 8 < K);
        float4 av, bv;
        if (more) {
            av = *(const float4*)(A + (size_t)(m0 + arow) * K + (k0 + 8) + ahalf);
            if (TRANSB) bv = *(const float4*)(Bm + (size_t)(n0 + arow) * K + (k0 + 8) + ahalf);
            else        bv = *(const float4*)(Bm + (size_t)(k0 + 8 + bk) * N + n0 + bn);
        }
#pragma unroll
        for (int k = 0; k < 8; k++) {
            float a[8], bb[8];
            *(float4*)&a[0]  = *(const float4*)&As[cur][k][ty * 8];
            *(float4*)&a[4]  = *(const float4*)&As[cur][k][ty * 8 + 4];
            *(float4*)&bb[0] = *(const float4*)&Bs[cur][k][tx * 8];
            *(float4*)&bb[4] = *(const float4*)&Bs[cur][k][tx * 8 + 4];
#pragma unroll
            for (int i = 0; i < 8; i++)
#pragma unroll
                for (int j = 0; j < 8; j++)
                    acc[i][j] = fmaf(a[i], bb[j], acc[i][j]);
        }
        if (more) {
            const int nxt = cur ^ 1;
            As[nxt][ahalf + 0][arow] = av.x;
            As[nxt][ahalf + 1][arow] = av.y;
            As[nxt][ahalf + 2][arow] = av.z;
            As[nxt][ahalf + 3][arow] = av.w;
            if (TRANSB) {
                Bs[nxt][ahalf + 0][arow] = bv.x;
                Bs[nxt][ahalf + 1][arow] = bv.y;
                Bs[nxt][ahalf + 2][arow] = bv.z;
                Bs[nxt][ahalf + 3][arow] = bv.w;
            } else {
                *(float4*)&Bs[nxt][bk][bn] = bv;
            }
        }
        __syncthreads();
        cur ^= 1;
    }

    float bia[8];
#pragma unroll
    for (int j = 0; j < 8; j++) {
        int gn = n0 + tx * 8 + j;
        bia[j] = bias1[gn] + (bias2 ? bias2[gn] : 0.f);
    }
#pragma unroll
    for (int i = 0; i < 8; i++) {
        size_t row = (size_t)(m0 + ty * 8 + i) * N + n0 + tx * 8;
#pragma unroll
        for (int j = 0; j < 8; j++)
            C[row + j] = acc[i][j] + bia[j];
    }
}

// ---------------------------------------------------------------------------
// Exclusive scan of word lengths per batch (N_=512 words, one block per batch)
// ---------------------------------------------------------------------------
__global__ __launch_bounds__(512) void scan_lens(const int* __restrict__ lens,
                                                 int* __restrict__ off)
{
    const int b = blockIdx.x, t = threadIdx.x;
    __shared__ int s[512];
    int v = lens[b * N_ + t];
    s[t] = v;
    __syncthreads();
    for (int d = 1; d < 512; d <<= 1) {
        int u = (t >= d) ? s[t - d] : 0;
        __syncthreads();
        s[t] += u;
        __syncthreads();
    }
    off[b * N_ + t] = s[t] - v;   // exclusive prefix
}

// ---------------------------------------------------------------------------
// dec_char gather + zero-fill of the pad half (replaces the 16 MB memset)
// ---------------------------------------------------------------------------
__global__ __launch_bounds__(256) void char_gather(const int* __restrict__ ids,
                                                   const float* __restrict__ emb,
                                                   float* __restrict__ x)
{
    int g   = blockIdx.x * 8 + (threadIdx.x >> 5);   // (b,l) flat, 8 per block
    int l32 = threadIdx.x & 31;
    int id  = ids[g];
    float4 v;
    if (l32 < 16) v = *(const float4*)(emb + (size_t)id * CE_ + l32 * 4);
    else          v = make_float4(0.f, 0.f, 0.f, 0.f);
    *(float4*)(x + (size_t)g * XDIM_ + l32 * 4) = v;
}

// ---------------------------------------------------------------------------
// Ragged scatter: x[b, off+m, 64+c] = rep[b,n,m,c] for m < len, off+m < L
// ---------------------------------------------------------------------------
__global__ __launch_bounds__(512) void scatter_pad(const float* __restrict__ rep,
                                                   const int* __restrict__ lens,
                                                   const int* __restrict__ off,
                                                   float* __restrict__ x)
{
    int word = blockIdx.x;            // b*512 + n
    int b = word >> 9;
    int m  = threadIdx.x >> 6;
    int cc = threadIdx.x & 63;
    int len = lens[word];
    if (m < len) {
        int dst = off[word] + m;
        if (dst < L_) {
            x[((size_t)b * L_ + dst) * XDIM_ + CE_ + cc] =
                rep[((size_t)word * M_ + m) * CE_ + cc];
        }
    }
}

// ---------------------------------------------------------------------------
// LSTM recurrence, R8 = R6's proven 8-wave structure + R7's validated issue
// diet. One block per batch (16 blocks, 512 thr = 8 waves, 2 waves/SIMD).
//
// Evidence so far:
//  R6 (8 waves):       step 1085 cyc = ~580 issue + ~505 exposed serial.
//  R7 (4 waves, diet): step 1165 cyc = ~320 issue + ~845 exposed -> 1 wave/
//    SIMD exposes the full serial path; 2 waves/SIMD interleave it. The
//    serial core is the LDS round-trip at the barrier (h write-drain +
//    barrier + ds_read ~300) + activation spine (~150) -- structural.
// R8: keep 8 waves; graft the diet only:
//  - persistent accumulators: C-in regs 1..3 are never read -> initialize
//    once, write only reg0 per step (6 movs, was ~20);
//  - gx prefetch via one pointer advanced 2048 B/step, gate offsets as
//    13-bit immediates; tail clamp dropped (<=4-row overrun reads land in
//    the unused upper half of d_out: gx is 64 MiB of the 128 MiB buffer);
//  - hs store via advanced pointer.
// ---------------------------------------------------------------------------
__global__ __launch_bounds__(512) void lstm_rec(const float* __restrict__ gx,   // [B,L,512]
                                                const float* __restrict__ Whh,  // [512,128]
                                                float* __restrict__ hs)         // [B,L,128]
{
    const int b    = blockIdx.x;
    const int tid  = threadIdx.x;
    const int wave = tid >> 6, lane = tid & 63;
    const int quad = lane >> 4, l15 = lane & 15;
    const int j    = wave * 16 + l15;          // hidden index owned by this lane

    __shared__ __align__(16) unsigned short hbuf[2][128];
    if (tid < 128) hbuf[0][tid] = 0;           // h_{-1} = 0 (bf16 zero bits)

    // B fragments: bfrag[q][kk] holds W_hh[q*128 + j][kk*32 + quad*8 + 0..7] (bf16)
    bf16x8 bfrag[4][4];
#pragma unroll
    for (int q = 0; q < 4; q++) {
        const float* wrow = Whh + (size_t)(q * 128 + j) * H_;
#pragma unroll
        for (int kk = 0; kk < 4; kk++) {
            int kb = kk * 32 + quad * 8;
            float4 w0 = *(const float4*)(wrow + kb);
            float4 w1 = *(const float4*)(wrow + kb + 4);
            union { unsigned short u[8]; bf16x8 v; } U;
            U.u[0] = f2bf(w0.x); U.u[1] = f2bf(w0.y); U.u[2] = f2bf(w0.z); U.u[3] = f2bf(w0.w);
            U.u[4] = f2bf(w1.x); U.u[5] = f2bf(w1.y); U.u[6] = f2bf(w1.z); U.u[7] = f2bf(w1.w);
            bfrag[q][kk] = U.v;
        }
    }

    // gx prefetch ring (depth 4) via pointer-advance: gp tracks row t+4, col j.
    const float* gp = gx + (size_t)b * L_ * G4_ + j;
    float pf[4][4];
#pragma unroll
    for (int u = 0; u < 4; u++)
#pragma unroll
        for (int q = 0; q < 4; q++)
            pf[u][q] = gp[(size_t)u * G4_ + q * 128];
    gp += 4 * G4_;

    // persistent accumulators: regs 1..3 written by MFMA, never read by us.
    f32x4 accga = {0.f, 0.f, 0.f, 0.f};
    f32x4 accgb = accga, acci = accga, accf = accga, acco = accga;

    float c = 0.f;
    float* hp = hs + (size_t)b * L_ * H_ + j;   // advanced H_ per step
    __syncthreads();   // hbuf init visible; drains prologue prefetch, ok

#define RCP_(x) __builtin_amdgcn_rcpf(x)
#define MFMA_(a, bb, cc) __builtin_amdgcn_mfma_f32_16x16x32_bf16(a, bb, cc, 0, 0, 0)

    for (int t0 = 0; t0 < L_; t0 += 4) {
#pragma unroll
        for (int u = 0; u < 4; u++) {
            const int pb = (t0 + u) & 1;

            // A fragments (h broadcast across rows)
            bf16x8 a0 = *(const bf16x8*)&hbuf[pb][0 * 32 + quad * 8];
            bf16x8 a1 = *(const bf16x8*)&hbuf[pb][1 * 32 + quad * 8];
            bf16x8 a2 = *(const bf16x8*)&hbuf[pb][2 * 32 + quad * 8];
            bf16x8 a3 = *(const bf16x8*)&hbuf[pb][3 * 32 + quad * 8];

            // write ONLY reg0 (gx pre-activation); regs 1..3 carry stale data
            accga[0] = pf[u][2];
            accgb[0] = 0.f;
            acci[0]  = pf[u][0];
            accf[0]  = pf[u][1];
            acco[0]  = pf[u][3];

            // refill slot u for t+4 (in flight across the raw barrier);
            // overrun past row L-1 lands in d_out's unused upper half.
#pragma unroll
            for (int q = 0; q < 4; q++) pf[u][q] = gp[q * 128];
            gp += G4_;

            // g first (two 2-deep chains -> earliest completion), then i, f, o
            accga = MFMA_(a0, bfrag[2][0], accga);
            accgb = MFMA_(a1, bfrag[2][1], accgb);
            acci  = MFMA_(a0, bfrag[0][0], acci);
            accf  = MFMA_(a0, bfrag[1][0], accf);
            acco  = MFMA_(a0, bfrag[3][0], acco);
            accga = MFMA_(a2, bfrag[2][2], accga);
            accgb = MFMA_(a3, bfrag[2][3], accgb);
            acci  = MFMA_(a1, bfrag[0][1], acci);
            accf  = MFMA_(a1, bfrag[1][1], accf);
            acco  = MFMA_(a1, bfrag[3][1], acco);
            acci  = MFMA_(a2, bfrag[0][2], acci);
            accf  = MFMA_(a2, bfrag[1][2], accf);
            acco  = MFMA_(a2, bfrag[3][2], acco);
            acci  = MFMA_(a3, bfrag[0][3], acci);
            accf  = MFMA_(a3, bfrag[1][3], accf);
            acco  = MFMA_(a3, bfrag[3][3], acco);

            // activations: raw v_rcp_f32 (no IEEE div sequence on the chain)
            float gg = accga[0] + accgb[0];
            float tg = 1.f - 2.f * RCP_(__expf(2.f * gg) + 1.f);
            float si = RCP_(1.f + __expf(-acci[0]));
            float sf = RCP_(1.f + __expf(-accf[0]));
            float so = RCP_(1.f + __expf(-acco[0]));
            c = sf * c + si * tg;
            float tc = 1.f - 2.f * RCP_(__expf(2.f * c) + 1.f);
            float h = so * tc;

            unsigned hr;
            asm("v_cvt_pk_bf16_f32 %0, %1, %2" : "=v"(hr) : "v"(h), "v"(h));
            if (quad == 0) {
                hbuf[pb ^ 1][j] = (unsigned short)hr;
                *hp = h;
            }
            hp += H_;
            // LDS-only drain + barrier (proven R2/R6 form)
            asm volatile("s_waitcnt lgkmcnt(0)\n\ts_barrier" ::: "memory");
        }
    }
#undef RCP_
#undef MFMA_
}

// ---------------------------------------------------------------------------
// Launch. Workspace layout (bytes):
//   rep : [0, 16 MiB)            8192 x 512 fp32
//   x   : [16 MiB, 32 MiB)       16 x 2048 x 128 fp32
//   hs  : [32 MiB, 48 MiB)       16 x 2048 x 128 fp32
//   off : [48 MiB, +32 KiB)      16 x 512 int
// gx (64 MiB) staged in d_out (128 MiB), consumed before the final GEMM;
// lstm_rec's prefetch may read <=4 rows past gx -- still inside d_out.
// ---------------------------------------------------------------------------
extern "C" void kernel_launch(void* const* d_in, const int* in_sizes, int n_in,
                              void* d_out, int out_size, void* d_ws, size_t ws_size,
                              hipStream_t stream)
{
    (void)in_sizes; (void)n_in; (void)out_size; (void)ws_size;
    const float* dec_hidden = (const float*)d_in[0];
    const int*   ids        = (const int*)d_in[1];
    const int*   lens       = (const int*)d_in[2];
    const float* char_emb   = (const float*)d_in[3];
    const float* W_proj     = (const float*)d_in[4];
    const float* b_proj     = (const float*)d_in[5];
    const float* W_ih       = (const float*)d_in[6];
    const float* W_hh       = (const float*)d_in[7];
    const float* b_ih       = (const float*)d_in[8];
    const float* b_hh       = (const float*)d_in[9];
    const float* W_pred     = (const float*)d_in[10];
    const float* b_pred     = (const float*)d_in[11];
    float* out = (float*)d_out;

    char* ws   = (char*)d_ws;
    float* rep = (float*)(ws);
    float* x   = (float*)(ws + (size_t)16 * 1024 * 1024);
    float* hs  = (float*)(ws + (size_t)32 * 1024 * 1024);
    int*   off = (int*)  (ws + (size_t)48 * 1024 * 1024);
    float* gx  = out;   // staged in output buffer, consumed before final GEMM

    // 1) rep = dec_hidden @ W_proj + b_proj   [8192,768]x[768,512]
    gemm_f32<false><<<dim3(4, 64), 256, 0, stream>>>(
        dec_hidden, W_proj, b_proj, nullptr, rep, B_ * N_, 512, DIM_);

    // 2) per-batch exclusive scan of word lengths
    scan_lens<<<B_, 512, 0, stream>>>(lens, off);

    // 3) build x = concat(char_emb[ids], 0-pad) then scatter rep into the pad
    char_gather<<<(B_ * L_) / 8, 256, 0, stream>>>(ids, char_emb, x);
    scatter_pad<<<B_ * N_, 512, 0, stream>>>(rep, lens, off, x);

    // 4) gx = x @ W_ih^T + b_ih + b_hh        [32768,128]x[512,128]^T
    gemm_f32<true><<<dim3(4, 256), 256, 0, stream>>>(
        x, W_ih, b_ih, b_hh, gx, B_ * L_, G4_, XDIM_);

    // 5) sequential LSTM (the critical path): 8 waves per batch
    lstm_rec<<<B_, 512, 0, stream>>>(gx, W_hh, hs);

    // 6) out = hs @ W_pred + b_pred           [32768,128]x[128,1024]
    gemm_f32<false><<<dim3(8, 256), 256, 0, stream>>>(
        hs, W_pred, b_pred, nullptr, out, B_ * L_, VOCAB_, H_);
}